// Round 9
// baseline (269.238 us; speedup 1.0000x reference)
//
#include <hip/hip_runtime.h>
#include <hip/hip_bf16.h>

// SegFormer block. R5: LN1 fused into consumers (k_ln1 deleted).
// R6: XCD-aware block swizzle on k_out (wid = (bid&7)<<8 | bid>>3).
// R7: FAILED (LDS cut; kernel was transaction-bound then) — reverted.
// R8: k_out lane-mapping swap: coalesced f loads (74->66us).
// R9: XCD swizzle on k_attn (batch b's 256 blocks -> XCD b, K/V L2-resident).
// R10: k_out branchless conv loads within a dy-row (66->57.6us).
// R11: ~neutral 2-deep row pipeline (57.6->56.0us).
// R12: REGRESSED (56->71us): two-stage gs + launch_bounds(256,3) caused VGPR
//     cap 84 -> scratch spills (WRITE 33->85MB, FETCH 41->69MB). Reverted.
// R13: R11 structure (single 32KB gs, 64KB LDS, (256,2)) + keep fast_gelu
//     (A&S erf, branch-free, verified absmax unchanged in R12 run).
// Workspace layout (total 105,988,096 <= ws):
//   [0,         16777216)  x2    bf16 (B,N,C)
//   [33554432,  33816576)  k     bf16 (B,Nr,C)
//   [33816576,  34078720)  vT    bf16 (B,C,Nr)
//   [34078720, 101187584)  f     bf16 (B,N,HID)
//   [101187584,101220352)  w1T   bf16 [n=256][k=64]  swizzled
//   [101220352,101253120)  w2T   bf16 [n=64][k=256]  swizzled
//   [101253120,101261312)  qwT   bf16 [n=64][k=64]   swizzled
//   [101261312,101269504)  pwT   bf16 [n=64][k=64]   swizzled
//   [101269504,101793792)  srwT  bf16 [n=64][k=4096] NOT swizzled
//   [101793792,105988096)  part  fp32 [8][2048][64]  sr-conv K-split partials
// swizzle: short at (row n, ch k) -> n*K + ((k>>3 ^ (n&7))<<3) + (k&7)

typedef __hip_bfloat16 bf16;
typedef __hip_bfloat162 bf162;
typedef __attribute__((ext_vector_type(8))) short s8v;
typedef __attribute__((ext_vector_type(4))) float f4v;

#define N_TOK 16384
#define CDIM 64
#define NR 256
#define HID 256
#define EPS 1e-5f

__device__ __forceinline__ float b2f(bf16 v) { return __bfloat162float(v); }
__device__ __forceinline__ bf16 f2b(float v) { return __float2bfloat16(v); }
__device__ __forceinline__ short bfbits(float f) {
  bf16 h = __float2bfloat16(f);
  return __builtin_bit_cast(short, h);
}
__device__ __forceinline__ float bits2f(short s) {
  return b2f(__builtin_bit_cast(bf16, s));
}

__device__ __forceinline__ float wred_sum(float v) {
#pragma unroll
  for (int o = 32; o >= 1; o >>= 1) v += __shfl_xor(v, o);
  return v;
}

// A&S 7.1.26 erf, branch-free, |err| <= 1.5e-7 (verified: absmax unchanged)
__device__ __forceinline__ float fast_gelu(float a) {
  const float ax = fabsf(a);
  const float t = __builtin_amdgcn_rcpf(fmaf(0.3275911f, ax, 1.f));
  float p = fmaf(1.061405429f, t, -1.453152027f);
  p = fmaf(p, t, 1.421413741f);
  p = fmaf(p, t, -0.284496736f);
  p = fmaf(p, t, 0.254829592f);
  p = p * t;
  const float y = fmaf(-p, __expf(-ax * ax), 1.f);   // erf(|a|)
  return 0.5f * a * (1.f + copysignf(y, a));
}

// ---------------- kernel 0: weight prep ----------------
// 1184 blocks x 256 thr, one element each.
__global__ __launch_bounds__(256) void k_prep(
    const float* __restrict__ qw, const float* __restrict__ pw,
    const float* __restrict__ w1, const float* __restrict__ w2,
    const float* __restrict__ srw,
    bf16* __restrict__ qwT, bf16* __restrict__ pwT,
    bf16* __restrict__ w1T, bf16* __restrict__ w2T,
    bf16* __restrict__ srwT) {
  int id = blockIdx.x * 256 + threadIdx.x;
  if (id < 4096) {
    const int n = id >> 6, k = id & 63;
    qwT[(n << 6) + ((((k >> 3) ^ (n & 7)) << 3)) + (k & 7)] = f2b(qw[(k << 6) + n]);
  } else if (id < 8192) {
    id -= 4096;
    const int n = id >> 6, k = id & 63;
    pwT[(n << 6) + ((((k >> 3) ^ (n & 7)) << 3)) + (k & 7)] = f2b(pw[(k << 6) + n]);
  } else if (id < 24576) {
    id -= 8192;
    const int n = id >> 6, k = id & 63;   // n in [0,256), k in [0,64)
    w1T[(n << 6) + ((((k >> 3) ^ (n & 7)) << 3)) + (k & 7)] = f2b(w1[(k << 8) + n]);
  } else if (id < 40960) {
    id -= 24576;
    const int n = id >> 8, k = id & 255;  // n in [0,64), k in [0,256)
    w2T[(n << 8) + ((((k >> 3) ^ (n & 7)) << 3)) + (k & 7)] = f2b(w2[(k << 6) + n]);
  } else {
    id -= 40960;                          // [0, 262144)
    const int n = id >> 12, k = id & 4095;
    srwT[(n << 12) + k] = f2b(srw[(k << 6) + n]);
  }
}

// ---------------- kernel 1: sr-conv GEMM (MFMA, 8-way K-split, LN1 fused) ----
// 512 blocks x 256 thr = 64 row-tiles (32 patches each) x 8 K-chunks.
__global__ __launch_bounds__(256) void k_srgemm(
    const float* __restrict__ x, const float* __restrict__ lng, const float* __restrict__ lnb,
    const bf16* __restrict__ srwT, float* __restrict__ part) {
  const int tid = threadIdx.x, lane = tid & 63, wv = tid >> 6;
  const int quad = lane >> 4, li = lane & 15;
  const int rt = blockIdx.x >> 3, ks = blockIdx.x & 7;
  const int pr = wv & 1, nh = wv >> 1;
  const int gp = (rt << 5) + (pr << 4) + li;      // global patch row (A: m=li)
  const int b = gp >> 8, pm = gp & 255;
  const int py = pm >> 4, px = pm & 15;
  const int n0 = (py << 10) + (px << 3);          // patch origin token
  const size_t abase = ((size_t)(b * N_TOK + n0)) << 6;

  float g0[8], e0[8], g1[8], e1[8];
#pragma unroll
  for (int j = 0; j < 8; j++) {
    g0[j] = lng[(quad << 3) + j];       e0[j] = lnb[(quad << 3) + j];
    g1[j] = lng[32 + (quad << 3) + j];  e1[j] = lnb[32 + (quad << 3) + j];
  }

  f4v acc[2];
  acc[0] = (f4v){0.f, 0.f, 0.f, 0.f};
  acc[1] = (f4v){0.f, 0.f, 0.f, 0.f};

#pragma unroll
  for (int t8 = 0; t8 < 8; t8++) {
    const int sp = (ks << 3) + t8;                // spatial tap 0..63
    const int nd = ((sp >> 3) << 7) + (sp & 7);   // token delta within patch
    const float* xp = x + abase + (((size_t)nd) << 6);
    float v0[8], v1[8];
    {
      const float4 l0 = *(const float4*)(xp + (quad << 3));
      const float4 l1 = *(const float4*)(xp + (quad << 3) + 4);
      const float4 l2 = *(const float4*)(xp + 32 + (quad << 3));
      const float4 l3 = *(const float4*)(xp + 32 + (quad << 3) + 4);
      v0[0] = l0.x; v0[1] = l0.y; v0[2] = l0.z; v0[3] = l0.w;
      v0[4] = l1.x; v0[5] = l1.y; v0[6] = l1.z; v0[7] = l1.w;
      v1[0] = l2.x; v1[1] = l2.y; v1[2] = l2.z; v1[3] = l2.w;
      v1[4] = l3.x; v1[5] = l3.y; v1[6] = l3.z; v1[7] = l3.w;
    }
    float s = 0.f;
#pragma unroll
    for (int j = 0; j < 8; j++) s += v0[j] + v1[j];
    s += __shfl_xor(s, 16); s += __shfl_xor(s, 32);
    const float mean = s * (1.f / 64.f);
    float vs = 0.f;
#pragma unroll
    for (int j = 0; j < 8; j++) {
      v0[j] -= mean; v1[j] -= mean;
      vs += v0[j] * v0[j] + v1[j] * v1[j];
    }
    vs += __shfl_xor(vs, 16); vs += __shfl_xor(vs, 32);
    const float rs = rsqrtf(vs * (1.f / 64.f) + EPS);
    s8v a0, a1;
#pragma unroll
    for (int j = 0; j < 8; j++) {
      a0[j] = bfbits(v0[j] * rs * g0[j] + e0[j]);
      a1[j] = bfbits(v1[j] * rs * g1[j] + e1[j]);
    }
    const int kk = (ks << 4) + (t8 << 1);         // k-step of 32 (even)
#pragma unroll
    for (int t = 0; t < 2; t++) {
      const int n = (nh << 5) + (t << 4) + li;
      s8v bv0 = *(const s8v*)(srwT + (((size_t)n) << 12) + (kk << 5) + (quad << 3));
      s8v bv1 = *(const s8v*)(srwT + (((size_t)n) << 12) + ((kk + 1) << 5) + (quad << 3));
      acc[t] = __builtin_amdgcn_mfma_f32_16x16x32_bf16(a0, bv0, acc[t], 0, 0, 0);
      acc[t] = __builtin_amdgcn_mfma_f32_16x16x32_bf16(a1, bv1, acc[t], 0, 0, 0);
    }
  }
  float* pp = part + (((size_t)ks) << 17);        // ks * 2048*64
#pragma unroll
  for (int t = 0; t < 2; t++)
#pragma unroll
    for (int r = 0; r < 4; r++) {
      const int row = (rt << 5) + (pr << 4) + (quad << 2) + r;  // C: row=quad*4+r
      pp[(row << 6) + (nh << 5) + (t << 4) + li] = acc[t][r];
    }
}

// ---------------- kernel 2: reduce partials + srnLN + kv projection ----------------
// 512 blocks x 256 thr; wave = one reduced token.
__global__ __launch_bounds__(256) void k_kv(
    const float* __restrict__ part, const float* __restrict__ srb,
    const float* __restrict__ sng, const float* __restrict__ snb,
    const float* __restrict__ kvw, const float* __restrict__ kvb,
    bf16* __restrict__ kbuf, bf16* __restrict__ vbufT) {
  const int tid = threadIdx.x, co = tid & 63, wv = tid >> 6;
  const int tok = (blockIdx.x << 2) + wv;
  float acc = srb[co];
#pragma unroll
  for (int s = 0; s < 8; s++) acc += part[(((size_t)s) << 17) + (tok << 6) + co];
  const float mean = wred_sum(acc) * (1.f / 64.f);
  const float d = acc - mean;
  const float var = wred_sum(d * d) * (1.f / 64.f);
  const float xn = d * rsqrtf(var + EPS) * sng[co] + snb[co];
  float ka = kvb[co];
  float va = kvb[64 + co];
#pragma unroll
  for (int ci = 0; ci < 64; ci++) {
    const float xv = __shfl(xn, ci);
    ka += xv * kvw[ci * 128 + co];
    va += xv * kvw[ci * 128 + 64 + co];
  }
  const int b = tok >> 8, nr = tok & 255;
  kbuf[(tok << 6) + co] = f2b(ka);
  vbufT[((((size_t)b << 6) + co) << 8) + nr] = f2b(va);
}

// ---------------- kernel 3: MFMA attention (LN1 fused for q-rows) ----------------
// R9: XCD swizzle — batch b's 256 blocks pinned to XCD b (K/V L2-resident).
__global__ __launch_bounds__(256) void k_attn(
    const float* __restrict__ x, const float* __restrict__ lng, const float* __restrict__ lnb,
    const bf16* __restrict__ qwT, const float* __restrict__ qb,
    const bf16* __restrict__ kbuf, const bf16* __restrict__ vbufT,
    const bf16* __restrict__ pwT, const float* __restrict__ pb,
    bf16* __restrict__ x2) {
  __shared__ __align__(16) short lds[36864];
  const int tid = threadIdx.x, lane = tid & 63, wv = tid >> 6;
  const int quad = lane >> 4, li = lane & 15;
  const int wid = ((blockIdx.x & 7) << 8) + (blockIdx.x >> 3);  // bijective, 2048%8==0
  const int b = wid >> 8;
  const int rowbase = ((wid & 255) << 6) + (wv << 4);

#pragma unroll
  for (int it = 0; it < 8; it++) {
    const int idx = (it << 8) + tid;
    {
      const int row = idx >> 3, c8 = idx & 7;
      uint4 d = *(const uint4*)(kbuf + (((size_t)(b * 256 + row)) << 6) + (c8 << 3));
      *(uint4*)&lds[(row << 6) + ((c8 ^ (row & 7)) << 3)] = d;
    }
    {
      const int row = idx >> 5, c8 = idx & 31;
      uint4 d = *(const uint4*)(vbufT + (((size_t)(b * 64 + row)) << 8) + (c8 << 3));
      *(uint4*)&lds[16384 + (row << 8) + ((c8 ^ (row & 7)) << 3)] = d;
    }
  }

  s8v qwf[2][4];
#pragma unroll
  for (int s = 0; s < 2; s++)
#pragma unroll
    for (int t = 0; t < 4; t++) {
      const int n = (t << 4) + li;
      qwf[s][t] = *(const s8v*)(qwT + (n << 6) + ((((s << 2) + quad) ^ (n & 7)) << 3));
    }

  // LN1(x) on the fly for this wave's 16 q-rows (row = rowbase+li).
  // The same 16x64 x tile is re-read (L1-hot) for the residual at the end.
  s8v ha[2];
  {
    const float* xr = x + (((size_t)(b * N_TOK + rowbase + li)) << 6);
    float v[16];
    const float4 l0 = *(const float4*)(xr + (quad << 3));
    const float4 l1 = *(const float4*)(xr + (quad << 3) + 4);
    const float4 l2 = *(const float4*)(xr + 32 + (quad << 3));
    const float4 l3 = *(const float4*)(xr + 32 + (quad << 3) + 4);
    v[0] = l0.x; v[1] = l0.y; v[2]  = l0.z; v[3]  = l0.w;
    v[4] = l1.x; v[5] = l1.y; v[6]  = l1.z; v[7]  = l1.w;
    v[8] = l2.x; v[9] = l2.y; v[10] = l2.z; v[11] = l2.w;
    v[12] = l3.x; v[13] = l3.y; v[14] = l3.z; v[15] = l3.w;
    float s = 0.f;
#pragma unroll
    for (int j = 0; j < 16; j++) s += v[j];
    s += __shfl_xor(s, 16); s += __shfl_xor(s, 32);
    const float mean = s * (1.f / 64.f);
    float vs = 0.f;
#pragma unroll
    for (int j = 0; j < 16; j++) { v[j] -= mean; vs += v[j] * v[j]; }
    vs += __shfl_xor(vs, 16); vs += __shfl_xor(vs, 32);
    const float rs = rsqrtf(vs * (1.f / 64.f) + EPS);
#pragma unroll
    for (int j = 0; j < 8; j++) {
      const int c0 = (quad << 3) + j, c1 = 32 + (quad << 3) + j;
      ha[0][j] = bfbits(v[j] * rs * lng[c0] + lnb[c0]);
      ha[1][j] = bfbits(v[8 + j] * rs * lng[c1] + lnb[c1]);
    }
  }

  f4v qacc[4];
#pragma unroll
  for (int t = 0; t < 4; t++) {
    const float bv = qb[(t << 4) + li];
    qacc[t] = (f4v){bv, bv, bv, bv};
  }
#pragma unroll
  for (int s = 0; s < 2; s++)
#pragma unroll
    for (int t = 0; t < 4; t++)
      qacc[t] = __builtin_amdgcn_mfma_f32_16x16x32_bf16(ha[s], qwf[s][t], qacc[t], 0, 0, 0);

  const int qoff = 32768 + (wv << 10);
#pragma unroll
  for (int t = 0; t < 4; t++)
#pragma unroll
    for (int r = 0; r < 4; r++) {
      const int m = (quad << 2) + r, c = (t << 4) + li;
      lds[qoff + (m << 6) + ((((c >> 3) ^ (m & 7)) << 3)) + (c & 7)] = bfbits(qacc[t][r] * 0.125f);
    }
  __syncthreads();

  s8v qa[2];
#pragma unroll
  for (int s = 0; s < 2; s++)
    qa[s] = *(const s8v*)&lds[qoff + (li << 6) + ((((s << 2) + quad) ^ (li & 7)) << 3)];

  f4v sv[16];
#pragma unroll
  for (int t = 0; t < 16; t++) sv[t] = (f4v){0.f, 0.f, 0.f, 0.f};
#pragma unroll
  for (int t = 0; t < 16; t++)
#pragma unroll
    for (int s = 0; s < 2; s++) {
      s8v kb = *(const s8v*)&lds[(((t << 4) + li) << 6) + ((((s << 2) + quad) ^ (li & 7)) << 3)];
      sv[t] = __builtin_amdgcn_mfma_f32_16x16x32_bf16(qa[s], kb, sv[t], 0, 0, 0);
    }

  float rl[4];
#pragma unroll
  for (int r = 0; r < 4; r++) {
    float mx = -1e30f;
#pragma unroll
    for (int t = 0; t < 16; t++) mx = fmaxf(mx, sv[t][r]);
#pragma unroll
    for (int o = 1; o <= 8; o <<= 1) mx = fmaxf(mx, __shfl_xor(mx, o));
    float sm = 0.f;
#pragma unroll
    for (int t = 0; t < 16; t++) {
      const float e = __expf(sv[t][r] - mx);
      sv[t][r] = e;
      sm += e;
    }
#pragma unroll
    for (int o = 1; o <= 8; o <<= 1) sm += __shfl_xor(sm, o);
    rl[r] = 1.0f / sm;
  }
  __syncthreads();

  const int poff = wv << 12;
#pragma unroll
  for (int t = 0; t < 16; t++)
#pragma unroll
    for (int r = 0; r < 4; r++) {
      const int m = (quad << 2) + r, c = (t << 4) + li;
      lds[poff + (m << 8) + (((c >> 3) ^ (m & 7)) << 3) + (c & 7)] = bfbits(sv[t][r]);
    }

  f4v oacc[4];
#pragma unroll
  for (int t = 0; t < 4; t++) oacc[t] = (f4v){0.f, 0.f, 0.f, 0.f};
#pragma unroll
  for (int s = 0; s < 8; s++) {
    s8v pa = *(const s8v*)&lds[poff + (li << 8) + ((((s << 2) + quad) ^ (li & 7)) << 3)];
#pragma unroll
    for (int t = 0; t < 4; t++) {
      s8v vb = *(const s8v*)&lds[16384 + (((t << 4) + li) << 8) + ((((s << 2) + quad) ^ (li & 7)) << 3)];
      oacc[t] = __builtin_amdgcn_mfma_f32_16x16x32_bf16(pa, vb, oacc[t], 0, 0, 0);
    }
  }

#pragma unroll
  for (int t = 0; t < 4; t++)
#pragma unroll
    for (int r = 0; r < 4; r++) {
      const int m = (quad << 2) + r, c = (t << 4) + li;
      lds[qoff + (m << 6) + (((c >> 3) ^ (m & 7)) << 3) + (c & 7)] = bfbits(oacc[t][r] * rl[r]);
    }
  s8v oa[2];
#pragma unroll
  for (int s = 0; s < 2; s++)
    oa[s] = *(const s8v*)&lds[qoff + (li << 6) + ((((s << 2) + quad) ^ (li & 7)) << 3)];

  f4v pacc[4];
#pragma unroll
  for (int t = 0; t < 4; t++) {
    const float bv = pb[(t << 4) + li];
    pacc[t] = (f4v){bv, bv, bv, bv};
  }
#pragma unroll
  for (int s = 0; s < 2; s++)
#pragma unroll
    for (int t = 0; t < 4; t++) {
      const int n = (t << 4) + li;
      s8v wf = *(const s8v*)(pwT + (n << 6) + ((((s << 2) + quad) ^ (n & 7)) << 3));
      pacc[t] = __builtin_amdgcn_mfma_f32_16x16x32_bf16(oa[s], wf, pacc[t], 0, 0, 0);
    }
#pragma unroll
  for (int t = 0; t < 4; t++)
#pragma unroll
    for (int r = 0; r < 4; r++) {
      const size_t gi = (((size_t)(b * N_TOK + rowbase + (quad << 2) + r)) << 6) + (t << 4) + li;
      x2[gi] = f2b(x[gi] + pacc[t][r]);
    }
}

// ---------------- kernel 4: LN2 + fc1 (MFMA) ----------------
__global__ __launch_bounds__(256) void k_fc1(
    const bf16* __restrict__ x2, const float* __restrict__ g, const float* __restrict__ bb,
    const bf16* __restrict__ w1T, const float* __restrict__ b1,
    bf16* __restrict__ f) {
  __shared__ __align__(16) short hs[4096];
  const int tid = threadIdx.x, lane = tid & 63, wv = tid >> 6;
  const int quad = lane >> 4, li = lane & 15;
  const int r0 = blockIdx.x << 6;

  s8v wf[2][4];
  float bv[4];
#pragma unroll
  for (int t = 0; t < 4; t++) {
    const int n = (((wv << 2) + t) << 4) + li;
    bv[t] = b1[n];
#pragma unroll
    for (int s = 0; s < 2; s++)
      wf[s][t] = *(const s8v*)(w1T + (n << 6) + ((((s << 2) + quad) ^ (n & 7)) << 3));
  }

  const int row = tid >> 2, q4 = tid & 3;
  const bf16* xp = x2 + (((size_t)(r0 + row)) << 6) + (q4 << 4);
  s8v xa = *(const s8v*)xp;
  s8v xb = *(const s8v*)(xp + 8);
  float v[16];
#pragma unroll
  for (int j = 0; j < 8; j++) {
    v[j] = bits2f(xa[j]);
    v[8 + j] = bits2f(xb[j]);
  }
  float s = 0.f;
#pragma unroll
  for (int j = 0; j < 16; j++) s += v[j];
  s += __shfl_xor(s, 1); s += __shfl_xor(s, 2);
  const float mean = s * (1.f / 64.f);
  float vs = 0.f;
#pragma unroll
  for (int j = 0; j < 16; j++) { v[j] -= mean; vs += v[j] * v[j]; }
  vs += __shfl_xor(vs, 1); vs += __shfl_xor(vs, 2);
  const float rs = rsqrtf(vs * (1.f / 64.f) + EPS);
  s8v p0, p1;
#pragma unroll
  for (int j = 0; j < 16; j++) {
    const int c = (q4 << 4) + j;
    const short hb = bfbits(v[j] * rs * g[c] + bb[c]);
    if (j < 8) p0[j] = hb; else p1[j - 8] = hb;
  }
  {
    const int m7 = row & 7;
    *(s8v*)&hs[(row << 6) + (((q4 << 1) ^ m7) << 3)] = p0;
    *(s8v*)&hs[(row << 6) + ((((q4 << 1) + 1) ^ m7) << 3)] = p1;
  }
  __syncthreads();

  s8v qa[4][2];
#pragma unroll
  for (int rg = 0; rg < 4; rg++) {
    const int m = (rg << 4) + li;
#pragma unroll
    for (int s2 = 0; s2 < 2; s2++)
      qa[rg][s2] = *(const s8v*)&hs[(m << 6) + ((((s2 << 2) + quad) ^ (m & 7)) << 3)];
  }
  f4v acc[4][4];
#pragma unroll
  for (int rg = 0; rg < 4; rg++)
#pragma unroll
    for (int t = 0; t < 4; t++) acc[rg][t] = (f4v){bv[t], bv[t], bv[t], bv[t]};
#pragma unroll
  for (int rg = 0; rg < 4; rg++)
#pragma unroll
    for (int t = 0; t < 4; t++) {
      acc[rg][t] = __builtin_amdgcn_mfma_f32_16x16x32_bf16(qa[rg][0], wf[0][t], acc[rg][t], 0, 0, 0);
      acc[rg][t] = __builtin_amdgcn_mfma_f32_16x16x32_bf16(qa[rg][1], wf[1][t], acc[rg][t], 0, 0, 0);
    }
#pragma unroll
  for (int rg = 0; rg < 4; rg++)
#pragma unroll
    for (int t = 0; t < 4; t++)
#pragma unroll
      for (int r = 0; r < 4; r++) {
        const int rr = r0 + (rg << 4) + (quad << 2) + r;
        f[((size_t)rr << 8) + ((((wv << 2) + t) << 4)) + li] = f2b(acc[rg][t][r]);
      }
}

// ---------------- kernel 5: dw 3x3 + gelu + fc2 (MFMA) + residual ----------------
// R6: XCD swizzle. R8: coalesced f loads. R10: branchless x-clustering.
// R11: interior-y peel + 2-deep row pipeline. R13: fast_gelu (A&S erf).
__global__ __launch_bounds__(256, 2) void k_out(
    const bf16* __restrict__ f, const float* __restrict__ dww,
    const bf16* __restrict__ x2, const bf16* __restrict__ w2T,
    const float* __restrict__ fc2b, float* __restrict__ out) {
  __shared__ __align__(16) short gs[16384];
  __shared__ __align__(16) short w2s[16384];
  const int tid = threadIdx.x, lane = tid & 63, wv = tid >> 6;
  const int quad = lane >> 4, li = lane & 15;
  const int wid = ((blockIdx.x & 7) << 8) + (blockIdx.x >> 3);  // bijective, 2048%8==0
  const int b = wid >> 8;
  const int y = (wid >> 1) & 127;
  const int xh = wid & 1;

#pragma unroll
  for (int i = 0; i < 8; i++)
    ((uint4*)w2s)[(i << 8) + tid] = ((const uint4*)w2T)[(i << 8) + tid];

  const int tg = tid >> 4, cg = tid & 15;   // R8: x-group = high bits, ch-group = low bits
  float acc[4][16];
#pragma unroll
  for (int t = 0; t < 4; t++)
#pragma unroll
    for (int j = 0; j < 16; j++) acc[t][j] = 0.f;

  const int x0 = (xh << 6) + (tg << 2);
  // halo masks: only xi=-1 (i=0) at x0==0 and xi=+4 (i=5) at x0==124 are OOB
  const short mlo = (x0 - 1 >= 0) ? (short)0xFFFF : (short)0;
  const short mhi = (x0 + 4 <= 127) ? (short)0xFFFF : (short)0;

#define LOAD_ROW(yy, fa, fb)                                                   \
  {                                                                            \
    const bf16* frow = f + ((((size_t)(b * 128 + (yy))) << 7) << 8) + (cg << 4); \
    _Pragma("unroll")                                                          \
    for (int i = 0; i < 6; i++) {                                              \
      const int xx = x0 + i - 1;                                               \
      const int xc = xx < 0 ? 0 : (xx > 127 ? 127 : xx);                       \
      const bf16* fp = frow + (((size_t)xc) << 8);                             \
      fa[i] = *(const s8v*)fp;                                                 \
      fb[i] = *(const s8v*)(fp + 8);                                           \
    }                                                                          \
  }

#define COMP_ROW(dy, fa, fb)                                                   \
  {                                                                            \
    float dwr[3][16];                                                          \
    _Pragma("unroll")                                                          \
    for (int dx = 0; dx < 3; dx++) {                                           \
      const float4* wp = (const float4*)(dww + ((dy) * 3 + dx) * HID + (cg << 4)); \
      _Pragma("unroll")                                                        \
      for (int j4 = 0; j4 < 4; j4++) {                                         \
        const float4 w4 = wp[j4];                                              \
        dwr[dx][j4 * 4 + 0] = w4.x; dwr[dx][j4 * 4 + 1] = w4.y;                \
        dwr[dx][j4 * 4 + 2] = w4.z; dwr[dx][j4 * 4 + 3] = w4.w;                \
      }                                                                        \
    }                                                                          \
    _Pragma("unroll")                                                          \
    for (int j = 0; j < 8; j++) {                                              \
      fa[0][j] = (short)(fa[0][j] & mlo);                                      \
      fb[0][j] = (short)(fb[0][j] & mlo);                                      \
      fa[5][j] = (short)(fa[5][j] & mhi);                                      \
      fb[5][j] = (short)(fb[5][j] & mhi);                                      \
    }                                                                          \
    _Pragma("unroll")                                                          \
    for (int i = 0; i < 6; i++) {                                              \
      const int xi = i - 1;                                                    \
      float fv[16];                                                            \
      _Pragma("unroll")                                                        \
      for (int j = 0; j < 8; j++) { fv[j] = bits2f(fa[i][j]); fv[8 + j] = bits2f(fb[i][j]); } \
      _Pragma("unroll")                                                        \
      for (int dx = 0; dx < 3; dx++) {                                         \
        const int t = xi - dx + 1;                                             \
        if (t < 0 || t > 3) continue;                                          \
        _Pragma("unroll")                                                      \
        for (int j = 0; j < 16; j++) acc[t][j] += fv[j] * dwr[dx][j];          \
      }                                                                        \
    }                                                                          \
  }

  if (y >= 1 && y <= 126) {
    s8v faA[6], fbA[6], faB[6], fbB[6];
    LOAD_ROW(y - 1, faA, fbA);
    LOAD_ROW(y,     faB, fbB);
    COMP_ROW(0, faA, fbA);
    LOAD_ROW(y + 1, faA, fbA);
    COMP_ROW(1, faB, fbB);
    COMP_ROW(2, faA, fbA);
  } else {
    for (int dy = 0; dy < 3; dy++) {
      const int yy = y + dy - 1;
      if (yy < 0 || yy > 127) continue;
      s8v faA[6], fbA[6];
      LOAD_ROW(yy, faA, fbA);
      COMP_ROW(dy, faA, fbA);
    }
  }
#undef LOAD_ROW
#undef COMP_ROW

#pragma unroll
  for (int t = 0; t < 4; t++) {
    const int m = (tg << 2) + t;
    s8v p0, p1;
#pragma unroll
    for (int j = 0; j < 16; j++) {
      const float ge = fast_gelu(acc[t][j]);
      if (j < 8) p0[j] = bfbits(ge); else p1[j - 8] = bfbits(ge);
    }
    const int m7 = m & 7;
    *(s8v*)&gs[(m << 8) + (((cg << 1) ^ m7) << 3)] = p0;
    *(s8v*)&gs[(m << 8) + ((((cg << 1) + 1) ^ m7) << 3)] = p1;
  }
  __syncthreads();

  f4v oa2[4];
#pragma unroll
  for (int ct = 0; ct < 4; ct++) {
    const float bb2 = fc2b[(ct << 4) + li];
    oa2[ct] = (f4v){bb2, bb2, bb2, bb2};
  }
  const int m = (wv << 4) + li;
#pragma unroll
  for (int kc = 0; kc < 8; kc++) {
    const int ch = (kc << 2) + quad;
    s8v av = *(const s8v*)&gs[(m << 8) + ((ch ^ (m & 7)) << 3)];
#pragma unroll
    for (int ct = 0; ct < 4; ct++) {
      const int n = (ct << 4) + li;
      s8v bv2 = *(const s8v*)&w2s[(n << 8) + ((ch ^ (n & 7)) << 3)];
      oa2[ct] = __builtin_amdgcn_mfma_f32_16x16x32_bf16(av, bv2, oa2[ct], 0, 0, 0);
    }
  }
  const int tokbase = (b << 14) + (y << 7) + (xh << 6) + (wv << 4) + (quad << 2);
#pragma unroll
  for (int ct = 0; ct < 4; ct++)
#pragma unroll
    for (int r = 0; r < 4; r++) {
      const size_t gi = (((size_t)(tokbase + r)) << 6) + (ct << 4) + li;
      out[gi] = b2f(x2[gi]) + oa2[ct][r];
    }
}

extern "C" void kernel_launch(void* const* d_in, const int* in_sizes, int n_in,
                              void* d_out, int out_size, void* d_ws, size_t ws_size,
                              hipStream_t stream) {
  const float* x    = (const float*)d_in[0];
  const float* ln1g = (const float*)d_in[3];
  const float* ln1b = (const float*)d_in[4];
  const float* qw   = (const float*)d_in[5];
  const float* qb   = (const float*)d_in[6];
  const float* kvw  = (const float*)d_in[7];
  const float* kvb  = (const float*)d_in[8];
  const float* pw   = (const float*)d_in[9];
  const float* pb   = (const float*)d_in[10];
  const float* srw  = (const float*)d_in[11];
  const float* srb  = (const float*)d_in[12];
  const float* sng  = (const float*)d_in[13];
  const float* snb  = (const float*)d_in[14];
  const float* ln2g = (const float*)d_in[15];
  const float* ln2b = (const float*)d_in[16];
  const float* w1   = (const float*)d_in[17];
  const float* b1   = (const float*)d_in[18];
  const float* dww  = (const float*)d_in[19];
  const float* w2   = (const float*)d_in[20];
  const float* b2v  = (const float*)d_in[21];
  float* out = (float*)d_out;

  char* ws = (char*)d_ws;
  bf16*  x2    = (bf16*)ws;                    // 16,777,216 B
  bf16*  kbuf  = (bf16*)(ws + 33554432);       //    262,144 B
  bf16*  vbufT = (bf16*)(ws + 33816576);       //    262,144 B
  bf16*  fbuf  = (bf16*)(ws + 34078720);       // 67,108,864 B
  bf16*  w1T   = (bf16*)(ws + 101187584);      //     32,768 B
  bf16*  w2T   = (bf16*)(ws + 101220352);      //     32,768 B
  bf16*  qwT   = (bf16*)(ws + 101253120);      //      8,192 B
  bf16*  pwT   = (bf16*)(ws + 101261312);      //      8,192 B
  bf16*  srwT  = (bf16*)(ws + 101269504);      //    524,288 B
  float* part  = (float*)(ws + 101793792);     //  4,194,304 B

  k_prep  <<< 1184, 256, 0, stream>>>(qw, pw, w1, w2, srw, qwT, pwT, w1T, w2T, srwT);
  k_srgemm<<<  512, 256, 0, stream>>>(x, ln1g, ln1b, srwT, part);
  k_kv    <<<  512, 256, 0, stream>>>(part, srb, sng, snb, kvw, kvb, kbuf, vbufT);
  k_attn  <<< 2048, 256, 0, stream>>>(x, ln1g, ln1b, qwT, qb, kbuf, vbufT, pwT, pb, x2);
  k_fc1   <<< 2048, 256, 0, stream>>>(x2, ln2g, ln2b, w1T, b1, fbuf);
  k_out   <<< 2048, 256, 0, stream>>>(fbuf, dww, x2, w2T, b2v, out);
}

// Round 10
// 234.798 us; speedup vs baseline: 1.1467x; 1.1467x over previous
//
#include <hip/hip_runtime.h>
#include <hip/hip_bf16.h>

// SegFormer block. R5: LN1 fused into consumers (k_ln1 deleted).
// R6: XCD-aware block swizzle on k_out (wid = (bid&7)<<8 | bid>>3).
// R7: FAILED (LDS cut; kernel was transaction-bound then) — reverted.
// R8: k_out lane-mapping swap: coalesced f loads (74->66us).
// R9: XCD swizzle on k_attn (batch b's 256 blocks -> XCD b, K/V L2-resident).
// R10: k_out branchless conv loads within a dy-row (66->57.6us).
// R11: 2-deep row pipeline (57.6->56.0us). BEST verified: 234.96us total.
// R12: REGRESSED (71us): two-stage gs + bound(256,3) -> scratch spills.
// R13: REGRESSED (88us): fast_gelu alone (vs R11) -> scratch spills
//     (WRITE 33->119MB). Straight-line gelu lets the scheduler flatten all
//     64 instances -> live-range blowup. libm erff's internal CFG keeps the
//     loop structured. CONCLUSION: do not touch the gelu region; erff stays.
// R14: clean revert to R11 verbatim (best verified state).
// Workspace layout (total 105,988,096 <= ws):
//   [0,         16777216)  x2    bf16 (B,N,C)
//   [33554432,  33816576)  k     bf16 (B,Nr,C)
//   [33816576,  34078720)  vT    bf16 (B,C,Nr)
//   [34078720, 101187584)  f     bf16 (B,N,HID)
//   [101187584,101220352)  w1T   bf16 [n=256][k=64]  swizzled
//   [101220352,101253120)  w2T   bf16 [n=64][k=256]  swizzled
//   [101253120,101261312)  qwT   bf16 [n=64][k=64]   swizzled
//   [101261312,101269504)  pwT   bf16 [n=64][k=64]   swizzled
//   [101269504,101793792)  srwT  bf16 [n=64][k=4096] NOT swizzled
//   [101793792,105988096)  part  fp32 [8][2048][64]  sr-conv K-split partials
// swizzle: short at (row n, ch k) -> n*K + ((k>>3 ^ (n&7))<<3) + (k&7)

typedef __hip_bfloat16 bf16;
typedef __hip_bfloat162 bf162;
typedef __attribute__((ext_vector_type(8))) short s8v;
typedef __attribute__((ext_vector_type(4))) float f4v;

#define N_TOK 16384
#define CDIM 64
#define NR 256
#define HID 256
#define EPS 1e-5f

__device__ __forceinline__ float b2f(bf16 v) { return __bfloat162float(v); }
__device__ __forceinline__ bf16 f2b(float v) { return __float2bfloat16(v); }
__device__ __forceinline__ short bfbits(float f) {
  bf16 h = __float2bfloat16(f);
  return __builtin_bit_cast(short, h);
}
__device__ __forceinline__ float bits2f(short s) {
  return b2f(__builtin_bit_cast(bf16, s));
}

__device__ __forceinline__ float wred_sum(float v) {
#pragma unroll
  for (int o = 32; o >= 1; o >>= 1) v += __shfl_xor(v, o);
  return v;
}

// ---------------- kernel 0: weight prep ----------------
// 1184 blocks x 256 thr, one element each.
__global__ __launch_bounds__(256) void k_prep(
    const float* __restrict__ qw, const float* __restrict__ pw,
    const float* __restrict__ w1, const float* __restrict__ w2,
    const float* __restrict__ srw,
    bf16* __restrict__ qwT, bf16* __restrict__ pwT,
    bf16* __restrict__ w1T, bf16* __restrict__ w2T,
    bf16* __restrict__ srwT) {
  int id = blockIdx.x * 256 + threadIdx.x;
  if (id < 4096) {
    const int n = id >> 6, k = id & 63;
    qwT[(n << 6) + ((((k >> 3) ^ (n & 7)) << 3)) + (k & 7)] = f2b(qw[(k << 6) + n]);
  } else if (id < 8192) {
    id -= 4096;
    const int n = id >> 6, k = id & 63;
    pwT[(n << 6) + ((((k >> 3) ^ (n & 7)) << 3)) + (k & 7)] = f2b(pw[(k << 6) + n]);
  } else if (id < 24576) {
    id -= 8192;
    const int n = id >> 6, k = id & 63;   // n in [0,256), k in [0,64)
    w1T[(n << 6) + ((((k >> 3) ^ (n & 7)) << 3)) + (k & 7)] = f2b(w1[(k << 8) + n]);
  } else if (id < 40960) {
    id -= 24576;
    const int n = id >> 8, k = id & 255;  // n in [0,64), k in [0,256)
    w2T[(n << 8) + ((((k >> 3) ^ (n & 7)) << 3)) + (k & 7)] = f2b(w2[(k << 6) + n]);
  } else {
    id -= 40960;                          // [0, 262144)
    const int n = id >> 12, k = id & 4095;
    srwT[(n << 12) + k] = f2b(srw[(k << 6) + n]);
  }
}

// ---------------- kernel 1: sr-conv GEMM (MFMA, 8-way K-split, LN1 fused) ----
// 512 blocks x 256 thr = 64 row-tiles (32 patches each) x 8 K-chunks.
__global__ __launch_bounds__(256) void k_srgemm(
    const float* __restrict__ x, const float* __restrict__ lng, const float* __restrict__ lnb,
    const bf16* __restrict__ srwT, float* __restrict__ part) {
  const int tid = threadIdx.x, lane = tid & 63, wv = tid >> 6;
  const int quad = lane >> 4, li = lane & 15;
  const int rt = blockIdx.x >> 3, ks = blockIdx.x & 7;
  const int pr = wv & 1, nh = wv >> 1;
  const int gp = (rt << 5) + (pr << 4) + li;      // global patch row (A: m=li)
  const int b = gp >> 8, pm = gp & 255;
  const int py = pm >> 4, px = pm & 15;
  const int n0 = (py << 10) + (px << 3);          // patch origin token
  const size_t abase = ((size_t)(b * N_TOK + n0)) << 6;

  float g0[8], e0[8], g1[8], e1[8];
#pragma unroll
  for (int j = 0; j < 8; j++) {
    g0[j] = lng[(quad << 3) + j];       e0[j] = lnb[(quad << 3) + j];
    g1[j] = lng[32 + (quad << 3) + j];  e1[j] = lnb[32 + (quad << 3) + j];
  }

  f4v acc[2];
  acc[0] = (f4v){0.f, 0.f, 0.f, 0.f};
  acc[1] = (f4v){0.f, 0.f, 0.f, 0.f};

#pragma unroll
  for (int t8 = 0; t8 < 8; t8++) {
    const int sp = (ks << 3) + t8;                // spatial tap 0..63
    const int nd = ((sp >> 3) << 7) + (sp & 7);   // token delta within patch
    const float* xp = x + abase + (((size_t)nd) << 6);
    float v0[8], v1[8];
    {
      const float4 l0 = *(const float4*)(xp + (quad << 3));
      const float4 l1 = *(const float4*)(xp + (quad << 3) + 4);
      const float4 l2 = *(const float4*)(xp + 32 + (quad << 3));
      const float4 l3 = *(const float4*)(xp + 32 + (quad << 3) + 4);
      v0[0] = l0.x; v0[1] = l0.y; v0[2] = l0.z; v0[3] = l0.w;
      v0[4] = l1.x; v0[5] = l1.y; v0[6] = l1.z; v0[7] = l1.w;
      v1[0] = l2.x; v1[1] = l2.y; v1[2] = l2.z; v1[3] = l2.w;
      v1[4] = l3.x; v1[5] = l3.y; v1[6] = l3.z; v1[7] = l3.w;
    }
    float s = 0.f;
#pragma unroll
    for (int j = 0; j < 8; j++) s += v0[j] + v1[j];
    s += __shfl_xor(s, 16); s += __shfl_xor(s, 32);
    const float mean = s * (1.f / 64.f);
    float vs = 0.f;
#pragma unroll
    for (int j = 0; j < 8; j++) {
      v0[j] -= mean; v1[j] -= mean;
      vs += v0[j] * v0[j] + v1[j] * v1[j];
    }
    vs += __shfl_xor(vs, 16); vs += __shfl_xor(vs, 32);
    const float rs = rsqrtf(vs * (1.f / 64.f) + EPS);
    s8v a0, a1;
#pragma unroll
    for (int j = 0; j < 8; j++) {
      a0[j] = bfbits(v0[j] * rs * g0[j] + e0[j]);
      a1[j] = bfbits(v1[j] * rs * g1[j] + e1[j]);
    }
    const int kk = (ks << 4) + (t8 << 1);         // k-step of 32 (even)
#pragma unroll
    for (int t = 0; t < 2; t++) {
      const int n = (nh << 5) + (t << 4) + li;
      s8v bv0 = *(const s8v*)(srwT + (((size_t)n) << 12) + (kk << 5) + (quad << 3));
      s8v bv1 = *(const s8v*)(srwT + (((size_t)n) << 12) + ((kk + 1) << 5) + (quad << 3));
      acc[t] = __builtin_amdgcn_mfma_f32_16x16x32_bf16(a0, bv0, acc[t], 0, 0, 0);
      acc[t] = __builtin_amdgcn_mfma_f32_16x16x32_bf16(a1, bv1, acc[t], 0, 0, 0);
    }
  }
  float* pp = part + (((size_t)ks) << 17);        // ks * 2048*64
#pragma unroll
  for (int t = 0; t < 2; t++)
#pragma unroll
    for (int r = 0; r < 4; r++) {
      const int row = (rt << 5) + (pr << 4) + (quad << 2) + r;  // C: row=quad*4+r
      pp[(row << 6) + (nh << 5) + (t << 4) + li] = acc[t][r];
    }
}

// ---------------- kernel 2: reduce partials + srnLN + kv projection ----------------
// 512 blocks x 256 thr; wave = one reduced token.
__global__ __launch_bounds__(256) void k_kv(
    const float* __restrict__ part, const float* __restrict__ srb,
    const float* __restrict__ sng, const float* __restrict__ snb,
    const float* __restrict__ kvw, const float* __restrict__ kvb,
    bf16* __restrict__ kbuf, bf16* __restrict__ vbufT) {
  const int tid = threadIdx.x, co = tid & 63, wv = tid >> 6;
  const int tok = (blockIdx.x << 2) + wv;
  float acc = srb[co];
#pragma unroll
  for (int s = 0; s < 8; s++) acc += part[(((size_t)s) << 17) + (tok << 6) + co];
  const float mean = wred_sum(acc) * (1.f / 64.f);
  const float d = acc - mean;
  const float var = wred_sum(d * d) * (1.f / 64.f);
  const float xn = d * rsqrtf(var + EPS) * sng[co] + snb[co];
  float ka = kvb[co];
  float va = kvb[64 + co];
#pragma unroll
  for (int ci = 0; ci < 64; ci++) {
    const float xv = __shfl(xn, ci);
    ka += xv * kvw[ci * 128 + co];
    va += xv * kvw[ci * 128 + 64 + co];
  }
  const int b = tok >> 8, nr = tok & 255;
  kbuf[(tok << 6) + co] = f2b(ka);
  vbufT[((((size_t)b << 6) + co) << 8) + nr] = f2b(va);
}

// ---------------- kernel 3: MFMA attention (LN1 fused for q-rows) ----------------
// R9: XCD swizzle — batch b's 256 blocks pinned to XCD b (K/V L2-resident).
__global__ __launch_bounds__(256) void k_attn(
    const float* __restrict__ x, const float* __restrict__ lng, const float* __restrict__ lnb,
    const bf16* __restrict__ qwT, const float* __restrict__ qb,
    const bf16* __restrict__ kbuf, const bf16* __restrict__ vbufT,
    const bf16* __restrict__ pwT, const float* __restrict__ pb,
    bf16* __restrict__ x2) {
  __shared__ __align__(16) short lds[36864];
  const int tid = threadIdx.x, lane = tid & 63, wv = tid >> 6;
  const int quad = lane >> 4, li = lane & 15;
  const int wid = ((blockIdx.x & 7) << 8) + (blockIdx.x >> 3);  // bijective, 2048%8==0
  const int b = wid >> 8;
  const int rowbase = ((wid & 255) << 6) + (wv << 4);

#pragma unroll
  for (int it = 0; it < 8; it++) {
    const int idx = (it << 8) + tid;
    {
      const int row = idx >> 3, c8 = idx & 7;
      uint4 d = *(const uint4*)(kbuf + (((size_t)(b * 256 + row)) << 6) + (c8 << 3));
      *(uint4*)&lds[(row << 6) + ((c8 ^ (row & 7)) << 3)] = d;
    }
    {
      const int row = idx >> 5, c8 = idx & 31;
      uint4 d = *(const uint4*)(vbufT + (((size_t)(b * 64 + row)) << 8) + (c8 << 3));
      *(uint4*)&lds[16384 + (row << 8) + ((c8 ^ (row & 7)) << 3)] = d;
    }
  }

  s8v qwf[2][4];
#pragma unroll
  for (int s = 0; s < 2; s++)
#pragma unroll
    for (int t = 0; t < 4; t++) {
      const int n = (t << 4) + li;
      qwf[s][t] = *(const s8v*)(qwT + (n << 6) + ((((s << 2) + quad) ^ (n & 7)) << 3));
    }

  // LN1(x) on the fly for this wave's 16 q-rows (row = rowbase+li).
  // The same 16x64 x tile is re-read (L1-hot) for the residual at the end.
  s8v ha[2];
  {
    const float* xr = x + (((size_t)(b * N_TOK + rowbase + li)) << 6);
    float v[16];
    const float4 l0 = *(const float4*)(xr + (quad << 3));
    const float4 l1 = *(const float4*)(xr + (quad << 3) + 4);
    const float4 l2 = *(const float4*)(xr + 32 + (quad << 3));
    const float4 l3 = *(const float4*)(xr + 32 + (quad << 3) + 4);
    v[0] = l0.x; v[1] = l0.y; v[2]  = l0.z; v[3]  = l0.w;
    v[4] = l1.x; v[5] = l1.y; v[6]  = l1.z; v[7]  = l1.w;
    v[8] = l2.x; v[9] = l2.y; v[10] = l2.z; v[11] = l2.w;
    v[12] = l3.x; v[13] = l3.y; v[14] = l3.z; v[15] = l3.w;
    float s = 0.f;
#pragma unroll
    for (int j = 0; j < 16; j++) s += v[j];
    s += __shfl_xor(s, 16); s += __shfl_xor(s, 32);
    const float mean = s * (1.f / 64.f);
    float vs = 0.f;
#pragma unroll
    for (int j = 0; j < 16; j++) { v[j] -= mean; vs += v[j] * v[j]; }
    vs += __shfl_xor(vs, 16); vs += __shfl_xor(vs, 32);
    const float rs = rsqrtf(vs * (1.f / 64.f) + EPS);
#pragma unroll
    for (int j = 0; j < 8; j++) {
      const int c0 = (quad << 3) + j, c1 = 32 + (quad << 3) + j;
      ha[0][j] = bfbits(v[j] * rs * lng[c0] + lnb[c0]);
      ha[1][j] = bfbits(v[8 + j] * rs * lng[c1] + lnb[c1]);
    }
  }

  f4v qacc[4];
#pragma unroll
  for (int t = 0; t < 4; t++) {
    const float bv = qb[(t << 4) + li];
    qacc[t] = (f4v){bv, bv, bv, bv};
  }
#pragma unroll
  for (int s = 0; s < 2; s++)
#pragma unroll
    for (int t = 0; t < 4; t++)
      qacc[t] = __builtin_amdgcn_mfma_f32_16x16x32_bf16(ha[s], qwf[s][t], qacc[t], 0, 0, 0);

  const int qoff = 32768 + (wv << 10);
#pragma unroll
  for (int t = 0; t < 4; t++)
#pragma unroll
    for (int r = 0; r < 4; r++) {
      const int m = (quad << 2) + r, c = (t << 4) + li;
      lds[qoff + (m << 6) + ((((c >> 3) ^ (m & 7)) << 3)) + (c & 7)] = bfbits(qacc[t][r] * 0.125f);
    }
  __syncthreads();

  s8v qa[2];
#pragma unroll
  for (int s = 0; s < 2; s++)
    qa[s] = *(const s8v*)&lds[qoff + (li << 6) + ((((s << 2) + quad) ^ (li & 7)) << 3)];

  f4v sv[16];
#pragma unroll
  for (int t = 0; t < 16; t++) sv[t] = (f4v){0.f, 0.f, 0.f, 0.f};
#pragma unroll
  for (int t = 0; t < 16; t++)
#pragma unroll
    for (int s = 0; s < 2; s++) {
      s8v kb = *(const s8v*)&lds[(((t << 4) + li) << 6) + ((((s << 2) + quad) ^ (li & 7)) << 3)];
      sv[t] = __builtin_amdgcn_mfma_f32_16x16x32_bf16(qa[s], kb, sv[t], 0, 0, 0);
    }

  float rl[4];
#pragma unroll
  for (int r = 0; r < 4; r++) {
    float mx = -1e30f;
#pragma unroll
    for (int t = 0; t < 16; t++) mx = fmaxf(mx, sv[t][r]);
#pragma unroll
    for (int o = 1; o <= 8; o <<= 1) mx = fmaxf(mx, __shfl_xor(mx, o));
    float sm = 0.f;
#pragma unroll
    for (int t = 0; t < 16; t++) {
      const float e = __expf(sv[t][r] - mx);
      sv[t][r] = e;
      sm += e;
    }
#pragma unroll
    for (int o = 1; o <= 8; o <<= 1) sm += __shfl_xor(sm, o);
    rl[r] = 1.0f / sm;
  }
  __syncthreads();

  const int poff = wv << 12;
#pragma unroll
  for (int t = 0; t < 16; t++)
#pragma unroll
    for (int r = 0; r < 4; r++) {
      const int m = (quad << 2) + r, c = (t << 4) + li;
      lds[poff + (m << 8) + (((c >> 3) ^ (m & 7)) << 3) + (c & 7)] = bfbits(sv[t][r]);
    }

  f4v oacc[4];
#pragma unroll
  for (int t = 0; t < 4; t++) oacc[t] = (f4v){0.f, 0.f, 0.f, 0.f};
#pragma unroll
  for (int s = 0; s < 8; s++) {
    s8v pa = *(const s8v*)&lds[poff + (li << 8) + ((((s << 2) + quad) ^ (li & 7)) << 3)];
#pragma unroll
    for (int t = 0; t < 4; t++) {
      s8v vb = *(const s8v*)&lds[16384 + (((t << 4) + li) << 8) + ((((s << 2) + quad) ^ (li & 7)) << 3)];
      oacc[t] = __builtin_amdgcn_mfma_f32_16x16x32_bf16(pa, vb, oacc[t], 0, 0, 0);
    }
  }

#pragma unroll
  for (int t = 0; t < 4; t++)
#pragma unroll
    for (int r = 0; r < 4; r++) {
      const int m = (quad << 2) + r, c = (t << 4) + li;
      lds[qoff + (m << 6) + (((c >> 3) ^ (m & 7)) << 3) + (c & 7)] = bfbits(oacc[t][r] * rl[r]);
    }
  s8v oa[2];
#pragma unroll
  for (int s = 0; s < 2; s++)
    oa[s] = *(const s8v*)&lds[qoff + (li << 6) + ((((s << 2) + quad) ^ (li & 7)) << 3)];

  f4v pacc[4];
#pragma unroll
  for (int t = 0; t < 4; t++) {
    const float bv = pb[(t << 4) + li];
    pacc[t] = (f4v){bv, bv, bv, bv};
  }
#pragma unroll
  for (int s = 0; s < 2; s++)
#pragma unroll
    for (int t = 0; t < 4; t++) {
      const int n = (t << 4) + li;
      s8v wf = *(const s8v*)(pwT + (n << 6) + ((((s << 2) + quad) ^ (n & 7)) << 3));
      pacc[t] = __builtin_amdgcn_mfma_f32_16x16x32_bf16(oa[s], wf, pacc[t], 0, 0, 0);
    }
#pragma unroll
  for (int t = 0; t < 4; t++)
#pragma unroll
    for (int r = 0; r < 4; r++) {
      const size_t gi = (((size_t)(b * N_TOK + rowbase + (quad << 2) + r)) << 6) + (t << 4) + li;
      x2[gi] = f2b(x[gi] + pacc[t][r]);
    }
}

// ---------------- kernel 4: LN2 + fc1 (MFMA) ----------------
__global__ __launch_bounds__(256) void k_fc1(
    const bf16* __restrict__ x2, const float* __restrict__ g, const float* __restrict__ bb,
    const bf16* __restrict__ w1T, const float* __restrict__ b1,
    bf16* __restrict__ f) {
  __shared__ __align__(16) short hs[4096];
  const int tid = threadIdx.x, lane = tid & 63, wv = tid >> 6;
  const int quad = lane >> 4, li = lane & 15;
  const int r0 = blockIdx.x << 6;

  s8v wf[2][4];
  float bv[4];
#pragma unroll
  for (int t = 0; t < 4; t++) {
    const int n = (((wv << 2) + t) << 4) + li;
    bv[t] = b1[n];
#pragma unroll
    for (int s = 0; s < 2; s++)
      wf[s][t] = *(const s8v*)(w1T + (n << 6) + ((((s << 2) + quad) ^ (n & 7)) << 3));
  }

  const int row = tid >> 2, q4 = tid & 3;
  const bf16* xp = x2 + (((size_t)(r0 + row)) << 6) + (q4 << 4);
  s8v xa = *(const s8v*)xp;
  s8v xb = *(const s8v*)(xp + 8);
  float v[16];
#pragma unroll
  for (int j = 0; j < 8; j++) {
    v[j] = bits2f(xa[j]);
    v[8 + j] = bits2f(xb[j]);
  }
  float s = 0.f;
#pragma unroll
  for (int j = 0; j < 16; j++) s += v[j];
  s += __shfl_xor(s, 1); s += __shfl_xor(s, 2);
  const float mean = s * (1.f / 64.f);
  float vs = 0.f;
#pragma unroll
  for (int j = 0; j < 16; j++) { v[j] -= mean; vs += v[j] * v[j]; }
  vs += __shfl_xor(vs, 1); vs += __shfl_xor(vs, 2);
  const float rs = rsqrtf(vs * (1.f / 64.f) + EPS);
  s8v p0, p1;
#pragma unroll
  for (int j = 0; j < 16; j++) {
    const int c = (q4 << 4) + j;
    const short hb = bfbits(v[j] * rs * g[c] + bb[c]);
    if (j < 8) p0[j] = hb; else p1[j - 8] = hb;
  }
  {
    const int m7 = row & 7;
    *(s8v*)&hs[(row << 6) + (((q4 << 1) ^ m7) << 3)] = p0;
    *(s8v*)&hs[(row << 6) + ((((q4 << 1) + 1) ^ m7) << 3)] = p1;
  }
  __syncthreads();

  s8v qa[4][2];
#pragma unroll
  for (int rg = 0; rg < 4; rg++) {
    const int m = (rg << 4) + li;
#pragma unroll
    for (int s2 = 0; s2 < 2; s2++)
      qa[rg][s2] = *(const s8v*)&hs[(m << 6) + ((((s2 << 2) + quad) ^ (m & 7)) << 3)];
  }
  f4v acc[4][4];
#pragma unroll
  for (int rg = 0; rg < 4; rg++)
#pragma unroll
    for (int t = 0; t < 4; t++) acc[rg][t] = (f4v){bv[t], bv[t], bv[t], bv[t]};
#pragma unroll
  for (int rg = 0; rg < 4; rg++)
#pragma unroll
    for (int t = 0; t < 4; t++) {
      acc[rg][t] = __builtin_amdgcn_mfma_f32_16x16x32_bf16(qa[rg][0], wf[0][t], acc[rg][t], 0, 0, 0);
      acc[rg][t] = __builtin_amdgcn_mfma_f32_16x16x32_bf16(qa[rg][1], wf[1][t], acc[rg][t], 0, 0, 0);
    }
#pragma unroll
  for (int rg = 0; rg < 4; rg++)
#pragma unroll
    for (int t = 0; t < 4; t++)
#pragma unroll
      for (int r = 0; r < 4; r++) {
        const int rr = r0 + (rg << 4) + (quad << 2) + r;
        f[((size_t)rr << 8) + ((((wv << 2) + t) << 4)) + li] = f2b(acc[rg][t][r]);
      }
}

// ---------------- kernel 5: dw 3x3 + gelu + fc2 (MFMA) + residual ----------------
// R6: XCD swizzle. R8: coalesced f loads. R10: branchless x-clustering.
// R11: interior-y peel + 2-deep row pipeline. Gelu region: libm erff ONLY
// (R12/R13 both proved straight-line gelu variants trigger scratch spills).
__global__ __launch_bounds__(256, 2) void k_out(
    const bf16* __restrict__ f, const float* __restrict__ dww,
    const bf16* __restrict__ x2, const bf16* __restrict__ w2T,
    const float* __restrict__ fc2b, float* __restrict__ out) {
  __shared__ __align__(16) short gs[16384];
  __shared__ __align__(16) short w2s[16384];
  const int tid = threadIdx.x, lane = tid & 63, wv = tid >> 6;
  const int quad = lane >> 4, li = lane & 15;
  const int wid = ((blockIdx.x & 7) << 8) + (blockIdx.x >> 3);  // bijective, 2048%8==0
  const int b = wid >> 8;
  const int y = (wid >> 1) & 127;
  const int xh = wid & 1;

#pragma unroll
  for (int i = 0; i < 8; i++)
    ((uint4*)w2s)[(i << 8) + tid] = ((const uint4*)w2T)[(i << 8) + tid];

  const int tg = tid >> 4, cg = tid & 15;   // R8: x-group = high bits, ch-group = low bits
  float acc[4][16];
#pragma unroll
  for (int t = 0; t < 4; t++)
#pragma unroll
    for (int j = 0; j < 16; j++) acc[t][j] = 0.f;

  const int x0 = (xh << 6) + (tg << 2);
  // halo masks: only xi=-1 (i=0) at x0==0 and xi=+4 (i=5) at x0==124 are OOB
  const short mlo = (x0 - 1 >= 0) ? (short)0xFFFF : (short)0;
  const short mhi = (x0 + 4 <= 127) ? (short)0xFFFF : (short)0;

#define LOAD_ROW(yy, fa, fb)                                                   \
  {                                                                            \
    const bf16* frow = f + ((((size_t)(b * 128 + (yy))) << 7) << 8) + (cg << 4); \
    _Pragma("unroll")                                                          \
    for (int i = 0; i < 6; i++) {                                              \
      const int xx = x0 + i - 1;                                               \
      const int xc = xx < 0 ? 0 : (xx > 127 ? 127 : xx);                       \
      const bf16* fp = frow + (((size_t)xc) << 8);                             \
      fa[i] = *(const s8v*)fp;                                                 \
      fb[i] = *(const s8v*)(fp + 8);                                           \
    }                                                                          \
  }

#define COMP_ROW(dy, fa, fb)                                                   \
  {                                                                            \
    float dwr[3][16];                                                          \
    _Pragma("unroll")                                                          \
    for (int dx = 0; dx < 3; dx++) {                                           \
      const float4* wp = (const float4*)(dww + ((dy) * 3 + dx) * HID + (cg << 4)); \
      _Pragma("unroll")                                                        \
      for (int j4 = 0; j4 < 4; j4++) {                                         \
        const float4 w4 = wp[j4];                                              \
        dwr[dx][j4 * 4 + 0] = w4.x; dwr[dx][j4 * 4 + 1] = w4.y;                \
        dwr[dx][j4 * 4 + 2] = w4.z; dwr[dx][j4 * 4 + 3] = w4.w;                \
      }                                                                        \
    }                                                                          \
    _Pragma("unroll")                                                          \
    for (int j = 0; j < 8; j++) {                                              \
      fa[0][j] = (short)(fa[0][j] & mlo);                                      \
      fb[0][j] = (short)(fb[0][j] & mlo);                                      \
      fa[5][j] = (short)(fa[5][j] & mhi);                                      \
      fb[5][j] = (short)(fb[5][j] & mhi);                                      \
    }                                                                          \
    _Pragma("unroll")                                                          \
    for (int i = 0; i < 6; i++) {                                              \
      const int xi = i - 1;                                                    \
      float fv[16];                                                            \
      _Pragma("unroll")                                                        \
      for (int j = 0; j < 8; j++) { fv[j] = bits2f(fa[i][j]); fv[8 + j] = bits2f(fb[i][j]); } \
      _Pragma("unroll")                                                        \
      for (int dx = 0; dx < 3; dx++) {                                         \
        const int t = xi - dx + 1;                                             \
        if (t < 0 || t > 3) continue;                                          \
        _Pragma("unroll")                                                      \
        for (int j = 0; j < 16; j++) acc[t][j] += fv[j] * dwr[dx][j];          \
      }                                                                        \
    }                                                                          \
  }

  if (y >= 1 && y <= 126) {
    s8v faA[6], fbA[6], faB[6], fbB[6];
    LOAD_ROW(y - 1, faA, fbA);
    LOAD_ROW(y,     faB, fbB);
    COMP_ROW(0, faA, fbA);
    LOAD_ROW(y + 1, faA, fbA);
    COMP_ROW(1, faB, fbB);
    COMP_ROW(2, faA, fbA);
  } else {
    for (int dy = 0; dy < 3; dy++) {
      const int yy = y + dy - 1;
      if (yy < 0 || yy > 127) continue;
      s8v faA[6], fbA[6];
      LOAD_ROW(yy, faA, fbA);
      COMP_ROW(dy, faA, fbA);
    }
  }
#undef LOAD_ROW
#undef COMP_ROW

#pragma unroll
  for (int t = 0; t < 4; t++) {
    const int m = (tg << 2) + t;
    s8v p0, p1;
#pragma unroll
    for (int j = 0; j < 16; j++) {
      const float a = acc[t][j];
      const float ge = 0.5f * a * (1.f + erff(a * 0.70710678118654752f));
      if (j < 8) p0[j] = bfbits(ge); else p1[j - 8] = bfbits(ge);
    }
    const int m7 = m & 7;
    *(s8v*)&gs[(m << 8) + (((cg << 1) ^ m7) << 3)] = p0;
    *(s8v*)&gs[(m << 8) + ((((cg << 1) + 1) ^ m7) << 3)] = p1;
  }
  __syncthreads();

  f4v oa2[4];
#pragma unroll
  for (int ct = 0; ct < 4; ct++) {
    const float bb2 = fc2b[(ct << 4) + li];
    oa2[ct] = (f4v){bb2, bb2, bb2, bb2};
  }
  const int m = (wv << 4) + li;
#pragma unroll
  for (int kc = 0; kc < 8; kc++) {
    const int ch = (kc << 2) + quad;
    s8v av = *(const s8v*)&gs[(m << 8) + ((ch ^ (m & 7)) << 3)];
#pragma unroll
    for (int ct = 0; ct < 4; ct++) {
      const int n = (ct << 4) + li;
      s8v bv2 = *(const s8v*)&w2s[(n << 8) + ((ch ^ (n & 7)) << 3)];
      oa2[ct] = __builtin_amdgcn_mfma_f32_16x16x32_bf16(av, bv2, oa2[ct], 0, 0, 0);
    }
  }
  const int tokbase = (b << 14) + (y << 7) + (xh << 6) + (wv << 4) + (quad << 2);
#pragma unroll
  for (int ct = 0; ct < 4; ct++)
#pragma unroll
    for (int r = 0; r < 4; r++) {
      const size_t gi = (((size_t)(tokbase + r)) << 6) + (ct << 4) + li;
      out[gi] = b2f(x2[gi]) + oa2[ct][r];
    }
}

extern "C" void kernel_launch(void* const* d_in, const int* in_sizes, int n_in,
                              void* d_out, int out_size, void* d_ws, size_t ws_size,
                              hipStream_t stream) {
  const float* x    = (const float*)d_in[0];
  const float* ln1g = (const float*)d_in[3];
  const float* ln1b = (const float*)d_in[4];
  const float* qw   = (const float*)d_in[5];
  const float* qb   = (const float*)d_in[6];
  const float* kvw  = (const float*)d_in[7];
  const float* kvb  = (const float*)d_in[8];
  const float* pw   = (const float*)d_in[9];
  const float* pb   = (const float*)d_in[10];
  const float* srw  = (const float*)d_in[11];
  const float* srb  = (const float*)d_in[12];
  const float* sng  = (const float*)d_in[13];
  const float* snb  = (const float*)d_in[14];
  const float* ln2g = (const float*)d_in[15];
  const float* ln2b = (const float*)d_in[16];
  const float* w1   = (const float*)d_in[17];
  const float* b1   = (const float*)d_in[18];
  const float* dww  = (const float*)d_in[19];
  const float* w2   = (const float*)d_in[20];
  const float* b2v  = (const float*)d_in[21];
  float* out = (float*)d_out;

  char* ws = (char*)d_ws;
  bf16*  x2    = (bf16*)ws;                    // 16,777,216 B
  bf16*  kbuf  = (bf16*)(ws + 33554432);       //    262,144 B
  bf16*  vbufT = (bf16*)(ws + 33816576);       //    262,144 B
  bf16*  fbuf  = (bf16*)(ws + 34078720);       // 67,108,864 B
  bf16*  w1T   = (bf16*)(ws + 101187584);      //     32,768 B
  bf16*  w2T   = (bf16*)(ws + 101220352);      //     32,768 B
  bf16*  qwT   = (bf16*)(ws + 101253120);      //      8,192 B
  bf16*  pwT   = (bf16*)(ws + 101261312);      //      8,192 B
  bf16*  srwT  = (bf16*)(ws + 101269504);      //    524,288 B
  float* part  = (float*)(ws + 101793792);     //  4,194,304 B

  k_prep  <<< 1184, 256, 0, stream>>>(qw, pw, w1, w2, srw, qwT, pwT, w1T, w2T, srwT);
  k_srgemm<<<  512, 256, 0, stream>>>(x, ln1g, ln1b, srwT, part);
  k_kv    <<<  512, 256, 0, stream>>>(part, srb, sng, snb, kvw, kvb, kbuf, vbufT);
  k_attn  <<< 2048, 256, 0, stream>>>(x, ln1g, ln1b, qwT, qb, kbuf, vbufT, pwT, pb, x2);
  k_fc1   <<< 2048, 256, 0, stream>>>(x2, ln2g, ln2b, w1T, b1, fbuf);
  k_out   <<< 2048, 256, 0, stream>>>(fbuf, dww, x2, w2T, b2v, out);
}